// Round 9
// baseline (647.710 us; speedup 1.0000x reference)
//
#include <hip/hip_runtime.h>
#include <hip/hip_bf16.h>

typedef __attribute__((ext_vector_type(8))) short bf16x8;
typedef __attribute__((ext_vector_type(4))) float f32x4;

#define GQ 16
#define L_IN 4096
#define CB 1024
#define ZR 4100      // 4096 + 2 pad rows each side

__device__ __forceinline__ void gload16(const void* g, void* l) {
    __builtin_amdgcn_global_load_lds((const __attribute__((address_space(1))) void*)g,
                                     (__attribute__((address_space(3))) void*)l, 16, 0, 0);
}

#define SBR() do { asm volatile("" ::: "memory");                 \
                   __builtin_amdgcn_sched_barrier(0);             \
                   __builtin_amdgcn_s_barrier();                  \
                   __builtin_amdgcn_sched_barrier(0);             \
                   asm volatile("" ::: "memory"); } while (0)
#define LGKM() do { asm volatile("s_waitcnt lgkmcnt(0)" ::: "memory"); \
                    __builtin_amdgcn_sched_barrier(0); } while (0)
#define VMW(n) do { __builtin_amdgcn_sched_barrier(0); \
                    asm volatile("s_waitcnt vmcnt(" #n ")" ::: "memory"); \
                    __builtin_amdgcn_sched_barrier(0); } while (0)

#define MM(MH, NH) do {                                                          \
    __builtin_amdgcn_s_setprio(1);                                               \
    _Pragma("unroll") for (int j_ = 0; j_ < 4; ++j_)                             \
      _Pragma("unroll") for (int n_ = 0; n_ < 2; ++n_)                           \
        _Pragma("unroll") for (int s_ = 0; s_ < 2; ++s_)                         \
          acc[(MH)*4 + j_][(NH)*2 + n_] = __builtin_amdgcn_mfma_f32_16x16x32_bf16( \
              af[j_][s_], bq[(NH)*2 + n_][s_], acc[(MH)*4 + j_][(NH)*2 + n_],    \
              0, 0, 0);                                                          \
    __builtin_amdgcn_s_setprio(0);                                               \
} while (0)

// Composite-weight term tables: slice s = P*5+j (j: z-row m'+j-2), terms are
// (kk, tap) with kk+tap = 2j+1-P. CC[P][j] = sum_terms Wh[kk] . WupT[tap].
__device__ const int TERM_KK[28]  = {0,1, 0,1,2,3, 2,3,4,5, 4,5,6, 6,
                                     0, 0,1,2, 1,2,3,4, 3,4,5,6, 5,6};
__device__ const int TERM_TAP[28] = {1,0, 3,2,1,0, 3,2,1,0, 3,2,1, 3,
                                     0, 2,1,0, 3,2,1,0, 3,2,1,0, 3,2};
__device__ const int SLICE_OFF[11] = {0,2,6,10,13,14,15,18,22,26,28};

// ---------------- zero pad rows of z ----------------
__global__ __launch_bounds__(256) void zero_pads_z(__hip_bfloat16* __restrict__ zp) {
    int idx = blockIdx.x * 256 + threadIdx.x;   // 4*4*1024
    int b = idx >> 12, r4 = (idx >> 10) & 3, c = idx & 1023;
    size_t row = (size_t)b * ZR + (r4 < 2 ? r4 : (ZR - 4 + r4));
    zp[row * 1024 + c] = __float2bfloat16(0.f);
}

// ---------------- repacks ----------------
// W_head OIH [o=512][cu][kk=7] -> Whr[kk][o][cu] bf16
__global__ __launch_bounds__(256) void repack_head(const float* __restrict__ Wh,
                                                   __hip_bfloat16* __restrict__ Wr) {
    int idx = blockIdx.x * 256 + threadIdx.x;   // 7*512*1024
    int kk = idx >> 19;
    int rem = idx & ((1 << 19) - 1);
    int o = rem >> 10;
    int cu = rem & 1023;
    Wr[idx] = __float2bfloat16(Wh[(o * 1024 + cu) * 7 + kk]);
}

// W_up IOH [cz][cu][tap=4] -> Wupt[tap][cz][cu] bf16 (float4 read, coalesced)
__global__ __launch_bounds__(256) void repack_upT(const float* __restrict__ Wup,
                                                  __hip_bfloat16* __restrict__ Wupt) {
    int idx = blockIdx.x * 256 + threadIdx.x;   // 1024*1024 (cz,cu)
    const float4 w = *(const float4*)&Wup[(size_t)idx * 4];
    Wupt[idx]           = __float2bfloat16(w.x);
    Wupt[1048576 + idx] = __float2bfloat16(w.y);
    Wupt[2097152 + idx] = __float2bfloat16(w.z);
    Wupt[3145728 + idx] = __float2bfloat16(w.w);
}

// ---------------- dequant + project -> z bf16 (2-row padded) ----------------
__global__ __launch_bounds__(256) void dequant_project(
    const int* __restrict__ indices, const float* __restrict__ codebooks,
    const float* __restrict__ scales, const float* __restrict__ Wout,
    const float* __restrict__ bout, __hip_bfloat16* __restrict__ z)
{
    __shared__ float w_lds[8192];
    __shared__ float b_lds[1024];
    __shared__ float part[128];
    __shared__ float summed[16];
    int tid = threadIdx.x;
    for (int k = tid; k < 8192; k += 256) w_lds[k] = Wout[k];
    for (int k = tid; k < 1024; k += 256) b_lds[k] = bout[k];
    int p0 = blockIdx.x * 16;
    int b  = p0 >> 12;
    int l0 = p0 & 4095;
    __syncthreads();
    for (int i = 0; i < 16; ++i) {
        int l = l0 + i;
        if (tid < 128) {
            int gq = tid >> 3;
            int d  = tid & 7;
            int idx = indices[(b * GQ + gq) * L_IN + l];
            float v = 0.f;
            if (idx >= 0) {
                int ic = (idx < CB) ? idx : 0;
                v = codebooks[(gq * CB + ic) * 8 + d] * scales[gq * 8 + d];
            }
            part[tid] = v;
        }
        __syncthreads();
        if (tid < 16) {
            int g = tid >> 3, d = tid & 7;
            float s = 0.f;
            for (int q = 0; q < 8; ++q) s += part[(g * 8 + q) * 8 + d];
            summed[tid] = s;
        }
        __syncthreads();
        #pragma unroll
        for (int j = 0; j < 4; ++j) {
            int c = tid + j * 256;
            int g = c >> 9;
            float acc = b_lds[c];
            #pragma unroll
            for (int d = 0; d < 8; ++d)
                acc += summed[g * 8 + d] * w_lds[(g * 8 + d) * 512 + (c & 511)];
            z[((size_t)b * ZR + l + 2) * 1024 + c] = __float2bfloat16(acc);
        }
        __syncthreads();
    }
}

// ---------------- combined bias: bt[o] = bh[o] + sum_kk,cu Wh[kk][o][cu]*bup[cu] ----
__global__ __launch_bounds__(64) void bias_combine(const float* __restrict__ Wh,
                                                   const float* __restrict__ bup,
                                                   const float* __restrict__ bh,
                                                   float* __restrict__ bt) {
    int o = blockIdx.x * 64 + threadIdx.x;      // 512
    float acc = bh[o];
    const float* wrow = Wh + (size_t)o * 7168;
    for (int cu = 0; cu < 1024; ++cu) {
        float ws = 0.f;
        #pragma unroll
        for (int kk = 0; kk < 7; ++kk) ws += wrow[cu * 7 + kk];
        acc += ws * bup[cu];
    }
    bt[o] = acc;
}

// ======= combine GEMM (per term): P32[g][o][cz] = Wh[kk][o][:] . WupT[tap][cz][:] =======
// R8-verified 8-phase skeleton, NT=16 (K=1024), 256x256 tile.
__global__ __launch_bounds__(512, 2) void combine_gemm(
    const __hip_bfloat16* __restrict__ Whr, const __hip_bfloat16* __restrict__ Wupt,
    float* __restrict__ P32)
{
    __shared__ __hip_bfloat16 Als[2][256][64];
    __shared__ __hip_bfloat16 Bls[2][256][64];
    const int tid = threadIdx.x;
    const int lane = tid & 63;
    const int w = tid >> 6;
    const int wm = w >> 2, wn = w & 3;
    const int l15 = lane & 15, kq = lane >> 4;
    const int g   = blockIdx.x;
    const int o0  = blockIdx.y * 256;
    const int cz0 = blockIdx.z * 256;
    const int NT = 16, NIT = 8;
    const int kk = TERM_KK[g], tap = TERM_TAP[g];

    const __hip_bfloat16* abase = Whr + ((size_t)kk * 512 + o0) * 1024;
    const __hip_bfloat16* bbase = Wupt + ((size_t)tap * 1024 + cz0) * 1024;

    auto stage = [&](int kt, int part) {
        if (kt >= NT) return;
        const int buf = kt & 1;
        const int ci0 = (kt & 15) << 6;
        const int rb = (part & 1) << 7;
        const __hip_bfloat16* src;
        __hip_bfloat16* dst;
        if (part < 2) { src = abase + (size_t)rb * 1024 + ci0; dst = &Als[buf][rb][0]; }
        else          { src = bbase + (size_t)rb * 1024 + ci0; dst = &Bls[buf][rb][0]; }
        #pragma unroll
        for (int it = 0; it < 2; ++it) {
            int chunk = it * 512 + tid;
            int row = chunk >> 3, cs = chunk & 7;
            int cq = cs ^ (row & 7);
            gload16(src + (size_t)row * 1024 + cq * 8,
                    (char*)dst + ((it * 512 + (w << 6)) << 4));
        }
    };

    f32x4 acc[8][4];
    const f32x4 z4 = {0.f, 0.f, 0.f, 0.f};
    #pragma unroll
    for (int i = 0; i < 8; ++i)
        #pragma unroll
        for (int j = 0; j < 4; ++j) acc[i][j] = z4;

    bf16x8 af[4][2], bq[4][2];

    auto rdA = [&](int buf, int mh) {
        #pragma unroll
        for (int j = 0; j < 4; ++j)
            #pragma unroll
            for (int sl = 0; sl < 2; ++sl) {
                int row = (wm << 7) + (mh << 6) + j * 16 + l15;
                int ch = (sl * 4 + kq) ^ (row & 7);
                af[j][sl] = *(const bf16x8*)&Als[buf][row][ch * 8];
            }
    };
    auto rdBlo = [&](int buf) {
        #pragma unroll
        for (int nf = 0; nf < 2; ++nf)
            #pragma unroll
            for (int sl = 0; sl < 2; ++sl) {
                int row = (wn << 6) + nf * 16 + l15;
                int ch = (sl * 4 + kq) ^ (row & 7);
                bq[nf][sl] = *(const bf16x8*)&Bls[buf][row][ch * 8];
            }
    };
    auto rdBhi = [&](int buf) {
        #pragma unroll
        for (int nf = 2; nf < 4; ++nf)
            #pragma unroll
            for (int sl = 0; sl < 2; ++sl) {
                int row = (wn << 6) + nf * 16 + l15;
                int ch = (sl * 4 + kq) ^ (row & 7);
                bq[nf][sl] = *(const bf16x8*)&Bls[buf][row][ch * 8];
            }
    };

    stage(0, 2); stage(0, 3); stage(0, 0); stage(0, 1);
    stage(1, 2); stage(1, 3); stage(1, 0);
    VMW(6);
    SBR();
    rdA(0, 0); rdBlo(0);

    for (int it = 0; it < NIT; ++it) {
        const bool lastit = (it == NIT - 1);
        stage(2 * it + 1, 1);
        SBR(); LGKM();
        MM(0, 0);
        rdBhi(0);
        SBR();
        stage(2 * it + 2, 2);
        SBR(); LGKM();
        MM(0, 1);
        rdA(0, 1);
        SBR();
        stage(2 * it + 2, 3);
        SBR(); LGKM();
        MM(1, 1);
        SBR();
        stage(2 * it + 2, 0);
        if (lastit) { VMW(0); } else { VMW(6); }
        SBR();
        MM(1, 0);
        rdA(1, 0); rdBlo(1);
        SBR();
        stage(2 * it + 2, 1);
        SBR(); LGKM();
        MM(0, 0);
        rdBhi(1);
        SBR();
        stage(2 * it + 3, 2);
        SBR(); LGKM();
        MM(0, 1);
        rdA(1, 1);
        SBR();
        stage(2 * it + 3, 3);
        SBR(); LGKM();
        MM(1, 1);
        SBR();
        stage(2 * it + 3, 0);
        if (!lastit) { VMW(6); }
        SBR();
        MM(1, 0);
        if (!lastit) { rdA(0, 0); rdBlo(0); }
        SBR();
    }

    const int obase = o0 + (wm << 7) + (kq << 2);
    const int czb = cz0 + (wn << 6) + l15;
    float* pg = P32 + (size_t)g * (512 * 1024);
    #pragma unroll
    for (int mf = 0; mf < 8; ++mf)
        #pragma unroll
        for (int e = 0; e < 4; ++e) {
            size_t rowoff = (size_t)(obase + mf * 16 + e) * 1024;
            #pragma unroll
            for (int nf = 0; nf < 4; ++nf)
                pg[rowoff + czb + nf * 16] = acc[mf][nf][e];
        }
}

// ---------------- reduce partials -> CC bf16 [s=P*5+j][o][cz] ----------------
__global__ __launch_bounds__(256) void reduce_cc(const float* __restrict__ P32,
                                                 __hip_bfloat16* __restrict__ CC) {
    int idx = blockIdx.x * 256 + threadIdx.x;   // 10*512*1024 = 5,242,880
    int s = idx >> 19;
    int r = idx & 524287;
    float sum = 0.f;
    for (int g = SLICE_OFF[s]; g < SLICE_OFF[s + 1]; ++g)
        sum += P32[(size_t)g * 524288 + r];
    CC[idx] = __float2bfloat16(sum);
}

// ======= fused main GEMM: out[b][o][2m'+P] = sum_j CC[P][j][o][:] . z[b][m'+j-2][:] =======
// R8-verified skeleton, NT=80 (K = 5*1024), A=CC (o), B=z rows (m').
__global__ __launch_bounds__(512, 2) void fused_main(
    const __hip_bfloat16* __restrict__ zp, const __hip_bfloat16* __restrict__ CC,
    const float* __restrict__ bt, float* __restrict__ out)
{
    __shared__ __hip_bfloat16 Als[2][256][64];
    __shared__ __hip_bfloat16 Bls[2][256][64];
    const int tid = threadIdx.x;
    const int lane = tid & 63;
    const int w = tid >> 6;
    const int wm = w >> 2, wn = w & 3;
    const int l15 = lane & 15, kq = lane >> 4;
    const int m0 = blockIdx.x * 256;
    const int o0 = blockIdx.y * 256;
    const int b = blockIdx.z >> 1, P = blockIdx.z & 1;
    const int NT = 80, NIT = 40;

    const __hip_bfloat16* abase = CC + (size_t)P * 5 * 512 * 1024;
    const __hip_bfloat16* bbase = zp + ((size_t)b * ZR + m0) * 1024;

    auto stage = [&](int kt, int part) {
        if (kt >= NT) return;
        const int buf = kt & 1;
        const int j = kt >> 4, ci0 = (kt & 15) << 6;
        const int rb = (part & 1) << 7;
        const __hip_bfloat16* src;
        __hip_bfloat16* dst;
        if (part < 2) { src = abase + ((size_t)(j * 512 + o0 + rb)) * 1024 + ci0;
                        dst = &Als[buf][rb][0]; }
        else          { src = bbase + ((size_t)(j + rb)) * 1024 + ci0;
                        dst = &Bls[buf][rb][0]; }
        #pragma unroll
        for (int it = 0; it < 2; ++it) {
            int chunk = it * 512 + tid;
            int row = chunk >> 3, cs = chunk & 7;
            int cq = cs ^ (row & 7);
            gload16(src + (size_t)row * 1024 + cq * 8,
                    (char*)dst + ((it * 512 + (w << 6)) << 4));
        }
    };

    f32x4 acc[8][4];
    const f32x4 z4 = {0.f, 0.f, 0.f, 0.f};
    #pragma unroll
    for (int i = 0; i < 8; ++i)
        #pragma unroll
        for (int j = 0; j < 4; ++j) acc[i][j] = z4;

    bf16x8 af[4][2], bq[4][2];

    auto rdA = [&](int buf, int mh) {
        #pragma unroll
        for (int j = 0; j < 4; ++j)
            #pragma unroll
            for (int sl = 0; sl < 2; ++sl) {
                int row = (wm << 7) + (mh << 6) + j * 16 + l15;
                int ch = (sl * 4 + kq) ^ (row & 7);
                af[j][sl] = *(const bf16x8*)&Als[buf][row][ch * 8];
            }
    };
    auto rdBlo = [&](int buf) {
        #pragma unroll
        for (int nf = 0; nf < 2; ++nf)
            #pragma unroll
            for (int sl = 0; sl < 2; ++sl) {
                int row = (wn << 6) + nf * 16 + l15;
                int ch = (sl * 4 + kq) ^ (row & 7);
                bq[nf][sl] = *(const bf16x8*)&Bls[buf][row][ch * 8];
            }
    };
    auto rdBhi = [&](int buf) {
        #pragma unroll
        for (int nf = 2; nf < 4; ++nf)
            #pragma unroll
            for (int sl = 0; sl < 2; ++sl) {
                int row = (wn << 6) + nf * 16 + l15;
                int ch = (sl * 4 + kq) ^ (row & 7);
                bq[nf][sl] = *(const bf16x8*)&Bls[buf][row][ch * 8];
            }
    };

    stage(0, 2); stage(0, 3); stage(0, 0); stage(0, 1);
    stage(1, 2); stage(1, 3); stage(1, 0);
    VMW(6);
    SBR();
    rdA(0, 0); rdBlo(0);

    for (int it = 0; it < NIT; ++it) {
        const bool lastit = (it == NIT - 1);
        stage(2 * it + 1, 1);
        SBR(); LGKM();
        MM(0, 0);
        rdBhi(0);
        SBR();
        stage(2 * it + 2, 2);
        SBR(); LGKM();
        MM(0, 1);
        rdA(0, 1);
        SBR();
        stage(2 * it + 2, 3);
        SBR(); LGKM();
        MM(1, 1);
        SBR();
        stage(2 * it + 2, 0);
        if (lastit) { VMW(0); } else { VMW(6); }
        SBR();
        MM(1, 0);
        rdA(1, 0); rdBlo(1);
        SBR();
        stage(2 * it + 2, 1);
        SBR(); LGKM();
        MM(0, 0);
        rdBhi(1);
        SBR();
        stage(2 * it + 3, 2);
        SBR(); LGKM();
        MM(0, 1);
        rdA(1, 1);
        SBR();
        stage(2 * it + 3, 3);
        SBR(); LGKM();
        MM(1, 1);
        SBR();
        stage(2 * it + 3, 0);
        if (!lastit) { VMW(6); }
        SBR();
        MM(1, 0);
        if (!lastit) { rdA(0, 0); rdBlo(0); }
        SBR();
    }

    const int obase = o0 + (wm << 7) + (kq << 2);
    const int tb = m0 + (wn << 6) + l15;
    #pragma unroll
    for (int mf = 0; mf < 8; ++mf)
        #pragma unroll
        for (int e = 0; e < 4; ++e) {
            int o = obase + mf * 16 + e;
            float bias = bt[o];
            size_t rowoff = ((size_t)(b * 512 + o)) * 8192 + P;
            #pragma unroll
            for (int nf = 0; nf < 4; ++nf)
                out[rowoff + 2 * (tb + nf * 16)] = acc[mf][nf][e] + bias;
        }
}

// ---------------- boundary fix-up ----------------
// Composite assumed formula-zu; real zu is zero-padded. Mismatch only at
// zu'[-1] = WupT[3].z[0] (affects t=0,1,2 via kk=2-t) and
// zu'[8192] = WupT[0].z[4095] (affects t=8189..8191 via kk=8195-t). Subtract.
__global__ __launch_bounds__(512) void fixup(const __hip_bfloat16* __restrict__ zp,
                                             const __hip_bfloat16* __restrict__ Wupt,
                                             const __hip_bfloat16* __restrict__ Whr,
                                             float* __restrict__ out) {
    __shared__ float zl[1024];
    __shared__ float vsh[1024];
    const int tid = threadIdx.x;
    const int side = blockIdx.x & 1, b = blockIdx.x >> 1;
    const int zrow = side ? 4097 : 2;     // padded idx of z[4095] / z[0]
    const int tap  = side ? 0 : 3;
    zl[tid]       = __bfloat162float(zp[((size_t)b * ZR + zrow) * 1024 + tid]);
    zl[tid + 512] = __bfloat162float(zp[((size_t)b * ZR + zrow) * 1024 + tid + 512]);
    __syncthreads();
    float a0 = 0.f, a1 = 0.f;
    const __hip_bfloat16* wt = Wupt + (size_t)tap * 1048576;
    for (int cz = 0; cz < 1024; ++cz) {
        float zv = zl[cz];
        a0 += zv * __bfloat162float(wt[(size_t)cz * 1024 + tid]);
        a1 += zv * __bfloat162float(wt[(size_t)cz * 1024 + tid + 512]);
    }
    vsh[tid] = a0; vsh[tid + 512] = a1;
    __syncthreads();
    const int lane = tid & 63, wv = tid >> 6;
    float vr[16];
    #pragma unroll
    for (int e = 0; e < 16; ++e) vr[e] = vsh[lane * 16 + e];
    for (int tt = 0; tt < 3; ++tt) {
        int t  = side ? (8189 + tt) : tt;
        int kk = side ? (6 - tt) : (2 - tt);
        for (int oo = 0; oo < 64; ++oo) {
            int o = wv * 64 + oo;
            const __hip_bfloat16* wr = Whr + ((size_t)kk * 512 + o) * 1024 + lane * 16;
            float p = 0.f;
            #pragma unroll
            for (int e = 0; e < 16; ++e) p += __bfloat162float(wr[e]) * vr[e];
            #pragma unroll
            for (int s = 32; s > 0; s >>= 1) p += __shfl_xor(p, s, 64);
            if (lane == 0) out[((size_t)(b * 512 + o)) * 8192 + t] -= p;
        }
    }
}

extern "C" void kernel_launch(void* const* d_in, const int* in_sizes, int n_in,
                              void* d_out, int out_size, void* d_ws, size_t ws_size,
                              hipStream_t stream) {
    const int*   indices   = (const int*)d_in[0];
    const float* codebooks = (const float*)d_in[1];
    const float* scales    = (const float*)d_in[2];
    const float* Wout      = (const float*)d_in[3];
    const float* bout      = (const float*)d_in[4];
    const float* Wup       = (const float*)d_in[5];
    const float* bup       = (const float*)d_in[6];
    const float* Wh        = (const float*)d_in[7];
    const float* bh        = (const float*)d_in[8];
    float* out = (float*)d_out;

    __hip_bfloat16* zp   = (__hip_bfloat16*)d_ws;                 // 4*4100*1024
    __hip_bfloat16* whr  = zp + (size_t)4 * ZR * 1024;            // 7*512*1024
    __hip_bfloat16* wupt = whr + (size_t)7 * 512 * 1024;          // 4*1024*1024
    __hip_bfloat16* cc   = wupt + (size_t)4 * 1024 * 1024;        // 10*512*1024
    float* p32 = (float*)(cc + (size_t)10 * 512 * 1024);          // 28*512*1024 f32
    float* bt  = p32 + (size_t)28 * 512 * 1024;                   // 512 f32

    zero_pads_z   <<<dim3(64),    dim3(256), 0, stream>>>(zp);
    repack_head   <<<dim3(14336), dim3(256), 0, stream>>>(Wh, whr);
    repack_upT    <<<dim3(4096),  dim3(256), 0, stream>>>(Wup, wupt);
    dequant_project<<<dim3(1024), dim3(256), 0, stream>>>(indices, codebooks, scales,
                                                          Wout, bout, zp);
    bias_combine  <<<dim3(8),     dim3(64),  0, stream>>>(Wh, bup, bh, bt);
    combine_gemm  <<<dim3(28, 2, 4), dim3(512), 0, stream>>>(whr, wupt, p32);
    reduce_cc     <<<dim3(20480), dim3(256), 0, stream>>>(p32, cc);
    fused_main    <<<dim3(16, 2, 8), dim3(512), 0, stream>>>(zp, cc, bt, out);
    fixup         <<<dim3(8),     dim3(512), 0, stream>>>(zp, wupt, whr, out);
}